// Round 20
// baseline (57.619 us; speedup 1.0000x reference)
//
#include <hip/hip_runtime.h>

// MSCA fused multi-scale depthwise conv chain, one workgroup per (b,c) plane.
// x:[8,256,64,64] f32 -> (attn_0, attn_1, attn_2) each [8,256,64,64] f32.
//
// R19 = R18 with the compile fix: __builtin_nontemporal_store needs a native
// clang vector type (ext_vector_type), not HIP's float4 class. Hypothesis
// unchanged: nt output stores (write-once, never re-read) free L2 for the
// x-plane reuse in P1 and stream the bursty P3 writes. Base is R14 (39.9us):
//  P1: 5x5 conv reading x DIRECT from global (5 guarded row ld8, L1-hot);
//      scatter ATT_T.                                                  B1
//  P2: read T-strip; a0y->a1y->a2y packed register chain; scatter Y0/Y1/Y2. B2
//  P3: staggered Y-row reads + packed x-chain + products + nt stores.
// 512 thr, 8 px/thread, strips of 8; DPP halos hoisted-then-selected.
// Transpose involution swizzle (R7-proven):
//   scatter:  buf[(8*lane8+e)*68 + (maj ^ (lane8<<3))]
//   strip rd: buf[maj*68 + ((lane8 ^ ((maj>>3)&7))<<3) + e]   (2x b128)
// LDS: RT (ATT_T), R0 (Y0), R1 (Y1), R2 (Y2) -- 4 x 4352 w = 69632 B.
// launch_bounds(512,4): VGPR cap 128 (spill law: never cap below ~90).

#define RW 4352                    // 64*68 per region
#define LDS_WORDS (4 * RW)         // 17408 words = 69632 B

typedef float v2f __attribute__((ext_vector_type(2)));
typedef float v4f __attribute__((ext_vector_type(4)));

__device__ __forceinline__ float dppsr1(float v) {   // lane i <- i-1 (16-lane rows)
    return __int_as_float(__builtin_amdgcn_update_dpp(
        0, __float_as_int(v), 0x111, 0xF, 0xF, false));
}
__device__ __forceinline__ float dppsr2(float v) {   // lane i <- i-2
    return __int_as_float(__builtin_amdgcn_update_dpp(
        0, __float_as_int(v), 0x112, 0xF, 0xF, false));
}
__device__ __forceinline__ float dppsl1(float v) {   // lane i <- i+1
    return __int_as_float(__builtin_amdgcn_update_dpp(
        0, __float_as_int(v), 0x101, 0xF, 0xF, false));
}
__device__ __forceinline__ float dppsl2(float v) {   // lane i <- i+2
    return __int_as_float(__builtin_amdgcn_update_dpp(
        0, __float_as_int(v), 0x102, 0xF, 0xF, false));
}
__device__ __forceinline__ void ld8(const float* p, float* d) {
    float4 a = *(const float4*)p, b = *(const float4*)(p + 4);
    d[0]=a.x; d[1]=a.y; d[2]=a.z; d[3]=a.w; d[4]=b.x; d[5]=b.y; d[6]=b.z; d[7]=b.w;
}
__device__ __forceinline__ void ld4p(const float* p, v2f* w) {
    float4 q = *(const float4*)p;
    w[0].x = q.x; w[0].y = q.y; w[1].x = q.z; w[1].y = q.w;
}
__device__ __forceinline__ void st4p_nt(float* p, v2f a, v2f b) {
    v4f q; q.x = a.x; q.y = a.y; q.z = b.x; q.w = b.y;
    __builtin_nontemporal_store(q, (v4f*)p);
}
__device__ __forceinline__ float elem(const v2f* a, int e) {
    return (e & 1) ? a[e >> 1].y : a[e >> 1].x;
}

// Packed conv (R3/R13-proven): window f[i] = wnd[i/2].{x,y}; out j=2k+{0,1}:
// A[k] += wt[v] * f[j + v + TAPOFF].
template<int K, int TAPOFF, int NP>
__device__ __forceinline__ void conv_acc(const float* __restrict__ wrow,
                                         const v2f* wnd, v2f* A) {
    #pragma unroll
    for (int v = 0; v < K; v++) {
        const float w = wrow[v];
        const int u = v + TAPOFF;
        if ((u & 1) == 0) {
            v2f wv; wv.x = w; wv.y = w;
            #pragma unroll
            for (int k = 0; k < NP; k++) A[k] += wv * wnd[(u >> 1) + k];
        } else {
            #pragma unroll
            for (int k = 0; k < NP; k++) {
                A[k].x += w * wnd[(u >> 1) + k].y;
                A[k].y += w * wnd[(u >> 1) + k + 1].x;
            }
        }
    }
}

// Packed strip conv, K=2H+1, H in {3,5}: halo lane+-1, hoisted then selected.
// Window f[0] = col j0-HE, HE = H+1 (even); TAPOFF = 1.
template<int H>
__device__ __forceinline__ void sconv_pk(const float* __restrict__ wt, float bb,
                                         const v2f* a, bool pm, bool np, v2f* acc) {
    constexpr int HE = H + 1;
    float pe[HE], ne[HE];
    pe[0] = 0.f;                       // pad slot (TAPOFF=1)
    #pragma unroll
    for (int i = 1; i < HE; i++) {     // cols j0-H .. j0-1 = prev elems 8-H..7
        float tmp = dppsr1(elem(a, 8 - HE + i));
        pe[i] = pm ? tmp : 0.f;
    }
    #pragma unroll
    for (int i = 0; i < H; i++) {      // cols j0+8 .. j0+8+H-1 = next elems 0..H-1
        float tmp = dppsl1(elem(a, i));
        ne[i] = np ? tmp : 0.f;
    }
    ne[H] = 0.f;
    v2f wnd[HE + 4];
    #pragma unroll
    for (int m = 0; m < HE / 2; m++) { wnd[m].x = pe[2 * m]; wnd[m].y = pe[2 * m + 1]; }
    #pragma unroll
    for (int k = 0; k < 4; k++) wnd[HE / 2 + k] = a[k];
    #pragma unroll
    for (int m = 0; m < HE / 2; m++) {
        wnd[HE / 2 + 4 + m].x = ne[2 * m]; wnd[HE / 2 + 4 + m].y = ne[2 * m + 1];
    }
    #pragma unroll
    for (int k = 0; k < 4; k++) { acc[k].x = bb; acc[k].y = bb; }
    conv_acc<2 * H + 1, 1, 4>(wt, wnd, acc);
}

// Packed 21-tap strip conv (H=10): halo lane+-1 (8 elems) + lane+-2 (2 elems).
// Window f[0] = col j0-10; TAPOFF = 0.
__device__ __forceinline__ void sconv21_pk(const float* __restrict__ wt, float bb,
                                           const v2f* a, bool pm, bool pm2,
                                           bool np, bool np2, v2f* acc) {
    float pe[10], ne[10];
    { float t0 = dppsr2(elem(a, 6)); pe[0] = pm2 ? t0 : 0.f; }
    { float t1 = dppsr2(elem(a, 7)); pe[1] = pm2 ? t1 : 0.f; }
    #pragma unroll
    for (int i = 0; i < 8; i++) {      // cols j0-8+i = prev elems 0..7
        float tmp = dppsr1(elem(a, i));
        pe[2 + i] = pm ? tmp : 0.f;
    }
    #pragma unroll
    for (int i = 0; i < 8; i++) {      // cols j0+8+i = next elems 0..7
        float tmp = dppsl1(elem(a, i));
        ne[i] = np ? tmp : 0.f;
    }
    { float t0 = dppsl2(elem(a, 0)); ne[8] = np2 ? t0 : 0.f; }
    { float t1 = dppsl2(elem(a, 1)); ne[9] = np2 ? t1 : 0.f; }
    v2f wnd[14];
    #pragma unroll
    for (int m = 0; m < 5; m++) { wnd[m].x = pe[2 * m]; wnd[m].y = pe[2 * m + 1]; }
    #pragma unroll
    for (int k = 0; k < 4; k++) wnd[5 + k] = a[k];
    #pragma unroll
    for (int m = 0; m < 5; m++) { wnd[9 + m].x = ne[2 * m]; wnd[9 + m].y = ne[2 * m + 1]; }
    #pragma unroll
    for (int k = 0; k < 4; k++) { acc[k].x = bb; acc[k].y = bb; }
    conv_acc<21, 0, 4>(wt, wnd, acc);
}

__global__ __launch_bounds__(512, 4)
void msca_fused(const float* __restrict__ x,
                const float* __restrict__ w0,   const float* __restrict__ b0,
                const float* __restrict__ w0_1, const float* __restrict__ b0_1,
                const float* __restrict__ w0_2, const float* __restrict__ b0_2,
                const float* __restrict__ w1_1, const float* __restrict__ b1_1,
                const float* __restrict__ w1_2, const float* __restrict__ b1_2,
                const float* __restrict__ w2_1, const float* __restrict__ b2_1,
                const float* __restrict__ w2_2, const float* __restrict__ b2_2,
                float* __restrict__ out)
{
    __shared__ __align__(16) float lds[LDS_WORDS];
    float* RT = lds;                // ATT_T
    float* R0 = lds + RW;           // Y0
    float* R1 = lds + 2 * RW;       // Y1
    float* R2 = lds + 3 * RW;       // Y2

    const int t     = threadIdx.x;     // 0..511
    const int maj   = t >> 3;          // X: image row ; T: image col
    const int lane8 = t & 7;
    const int j0    = lane8 << 3;

    const bool pm  = lane8 >= 1, np  = lane8 <= 6;
    const bool pm2 = lane8 >= 2, np2 = lane8 <= 5;

    const int scat = maj ^ (lane8 << 3);                           // scatter minor
    const int rdb  = maj * 68 + ((lane8 ^ ((maj >> 3) & 7)) << 3); // strip read base

    const int plane = blockIdx.x;
    const int ch    = plane & 255;

    const float* xg = x + (size_t)plane * 4096;
    float* o0 = out + (size_t)plane * 4096;
    float* o1 = o0 + 8388608;
    float* o2 = o1 + 8388608;

    // ---- P1: attn = conv5x5(x)+b0, x DIRECT from global (packed); ATT_T ----
    v2f attn[4];
    {
        const float bb = b0[ch];
        #pragma unroll
        for (int k = 0; k < 4; k++) { attn[k].x = bb; attn[k].y = bb; }
        const float* w0p = w0 + ch * 25;
        #pragma unroll
        for (int dr = 0; dr < 5; dr++) {
            const int ri = maj + dr - 2;
            const int rc = ri < 0 ? 0 : (ri > 63 ? 63 : ri);
            const bool valid = (unsigned)ri <= 63u;
            float a[8];
            ld8(&xg[rc * 64 + j0], a);
            #pragma unroll
            for (int i = 0; i < 8; i++) a[i] = valid ? a[i] : 0.f;  // row-edge zero
            float l0 = dppsr1(a[6]), l1 = dppsr1(a[7]);
            float r0 = dppsl1(a[0]), r1 = dppsl1(a[1]);
            v2f wnd[6];                       // cols j0-2 .. j0+9, f[0]=j0-2
            wnd[0].x = pm ? l0 : 0.f;  wnd[0].y = pm ? l1 : 0.f;
            wnd[1].x = a[0]; wnd[1].y = a[1];
            wnd[2].x = a[2]; wnd[2].y = a[3];
            wnd[3].x = a[4]; wnd[3].y = a[5];
            wnd[4].x = a[6]; wnd[4].y = a[7];
            wnd[5].x = np ? r0 : 0.f;  wnd[5].y = np ? r1 : 0.f;
            conv_acc<5, 0, 4>(w0p + dr * 5, wnd, attn);
        }
        #pragma unroll
        for (int e = 0; e < 8; e++) RT[(j0 + e) * 68 + scat] = elem(attn, e);
    }
    __syncthreads();   // B1 (ATT_T ready)

    // ---- P2: T-strip read; a0y -> a1y -> a2y packed chain; scatter Y0/Y1/Y2 ----
    {
        v2f stv[4];
        ld4p(&RT[rdb],     &stv[0]);
        ld4p(&RT[rdb + 4], &stv[2]);
        v2f a0y[4];
        sconv_pk<3>(w0_2 + ch * 7, b0_2[ch], stv, pm, np, a0y);
        #pragma unroll
        for (int d = 0; d < 8; d++) R0[(j0 + d) * 68 + scat] = elem(a0y, d);   // Y0
        v2f a1y[4];
        sconv_pk<5>(w1_2 + ch * 11, b1_2[ch], a0y, pm, np, a1y);
        #pragma unroll
        for (int d = 0; d < 8; d++) R1[(j0 + d) * 68 + scat] = elem(a1y, d);   // Y1
        v2f a2y[4];
        sconv21_pk(w2_2 + ch * 21, b2_2[ch], a1y, pm, pm2, np, np2, a2y);
        #pragma unroll
        for (int d = 0; d < 8; d++) R2[(j0 + d) * 68 + scat] = elem(a2y, d);   // Y2
    }
    __syncthreads();   // B2 (Y0/Y1/Y2 ready)

    // ---- P3: staggered Y reads; packed x-chain; products; nt stores ----
    {
        v2f y0r[4];
        ld4p(&R0[rdb],     &y0r[0]);       // issue; latency under a0x conv
        ld4p(&R0[rdb + 4], &y0r[2]);
        v2f a0x[4];
        sconv_pk<3>(w0_1 + ch * 7, b0_1[ch], attn, pm, np, a0x);
        {
            v2f q0 = a0x[0] * y0r[0], q1 = a0x[1] * y0r[1];
            v2f q2 = a0x[2] * y0r[2], q3 = a0x[3] * y0r[3];
            st4p_nt(&o0[maj * 64 + j0],     q0, q1);
            st4p_nt(&o0[maj * 64 + j0 + 4], q2, q3);
        }
        v2f y1r[4];
        ld4p(&R1[rdb],     &y1r[0]);       // issue; latency under a1x conv
        ld4p(&R1[rdb + 4], &y1r[2]);
        v2f a1x[4];
        sconv_pk<5>(w1_1 + ch * 11, b1_1[ch], a0x, pm, np, a1x);
        {
            v2f q0 = a1x[0] * y1r[0], q1 = a1x[1] * y1r[1];
            v2f q2 = a1x[2] * y1r[2], q3 = a1x[3] * y1r[3];
            st4p_nt(&o1[maj * 64 + j0],     q0, q1);
            st4p_nt(&o1[maj * 64 + j0 + 4], q2, q3);
        }
        v2f y2r[4];
        ld4p(&R2[rdb],     &y2r[0]);       // issue; latency under a2x conv
        ld4p(&R2[rdb + 4], &y2r[2]);
        v2f a2x[4];
        sconv21_pk(w2_1 + ch * 21, b2_1[ch], a1x, pm, pm2, np, np2, a2x);
        {
            v2f q0 = a2x[0] * y2r[0], q1 = a2x[1] * y2r[1];
            v2f q2 = a2x[2] * y2r[2], q3 = a2x[3] * y2r[3];
            st4p_nt(&o2[maj * 64 + j0],     q0, q1);
            st4p_nt(&o2[maj * 64 + j0 + 4], q2, q3);
        }
    }
}

extern "C" void kernel_launch(void* const* d_in, const int* in_sizes, int n_in,
                              void* d_out, int out_size, void* d_ws, size_t ws_size,
                              hipStream_t stream) {
    msca_fused<<<2048, 512, 0, stream>>>(
        (const float*)d_in[0],
        (const float*)d_in[1],  (const float*)d_in[2],
        (const float*)d_in[3],  (const float*)d_in[4],
        (const float*)d_in[5],  (const float*)d_in[6],
        (const float*)d_in[7],  (const float*)d_in[8],
        (const float*)d_in[9],  (const float*)d_in[10],
        (const float*)d_in[11], (const float*)d_in[12],
        (const float*)d_in[13], (const float*)d_in[14],
        (float*)d_out);
}

// Round 21
// 39.499 us; speedup vs baseline: 1.4587x; 1.4587x over previous
//
#include <hip/hip_runtime.h>

// MSCA fused multi-scale depthwise conv chain, one workgroup per (b,c) plane.
// x:[8,256,64,64] f32 -> (attn_0, attn_1, attn_2) each [8,256,64,64] f32.
//
// R20 = R14 verbatim (proven 39.9us best; R19's nt-store variant collapsed
// codegen to VGPR=52 + 66MB scratch spill -> reverted). 2 barriers:
//  P1: 5x5 conv reading x DIRECT from global (5 guarded row ld8, L1-hot);
//      scatter ATT_T.                                                  B1
//  P2: read T-strip; a0y->a1y->a2y packed register chain; scatter Y0/Y1/Y2. B2
//  P3: staggered Y-row reads + packed x-chain + products + stores.
// 512 thr, 8 px/thread, strips of 8; DPP halos hoisted-then-selected.
// Transpose involution swizzle (R7-proven):
//   scatter:  buf[(8*lane8+e)*68 + (maj ^ (lane8<<3))]
//   strip rd: buf[maj*68 + ((lane8 ^ ((maj>>3)&7))<<3) + e]   (2x b128)
// LDS: RT (ATT_T), R0 (Y0), R1 (Y1), R2 (Y2) -- 4 x 4352 w = 69632 B.
// launch_bounds(512,4): VGPR cap 128 (spill law: never cap below ~90).

#define RW 4352                    // 64*68 per region
#define LDS_WORDS (4 * RW)         // 17408 words = 69632 B

typedef float v2f __attribute__((ext_vector_type(2)));

__device__ __forceinline__ float dppsr1(float v) {   // lane i <- i-1 (16-lane rows)
    return __int_as_float(__builtin_amdgcn_update_dpp(
        0, __float_as_int(v), 0x111, 0xF, 0xF, false));
}
__device__ __forceinline__ float dppsr2(float v) {   // lane i <- i-2
    return __int_as_float(__builtin_amdgcn_update_dpp(
        0, __float_as_int(v), 0x112, 0xF, 0xF, false));
}
__device__ __forceinline__ float dppsl1(float v) {   // lane i <- i+1
    return __int_as_float(__builtin_amdgcn_update_dpp(
        0, __float_as_int(v), 0x101, 0xF, 0xF, false));
}
__device__ __forceinline__ float dppsl2(float v) {   // lane i <- i+2
    return __int_as_float(__builtin_amdgcn_update_dpp(
        0, __float_as_int(v), 0x102, 0xF, 0xF, false));
}
__device__ __forceinline__ void ld8(const float* p, float* d) {
    float4 a = *(const float4*)p, b = *(const float4*)(p + 4);
    d[0]=a.x; d[1]=a.y; d[2]=a.z; d[3]=a.w; d[4]=b.x; d[5]=b.y; d[6]=b.z; d[7]=b.w;
}
__device__ __forceinline__ void ld4p(const float* p, v2f* w) {
    float4 q = *(const float4*)p;
    w[0].x = q.x; w[0].y = q.y; w[1].x = q.z; w[1].y = q.w;
}
__device__ __forceinline__ void st4p(float* p, v2f a, v2f b) {
    float4 q; q.x = a.x; q.y = a.y; q.z = b.x; q.w = b.y;
    *(float4*)p = q;
}
__device__ __forceinline__ float elem(const v2f* a, int e) {
    return (e & 1) ? a[e >> 1].y : a[e >> 1].x;
}

// Packed conv (R3/R13-proven): window f[i] = wnd[i/2].{x,y}; out j=2k+{0,1}:
// A[k] += wt[v] * f[j + v + TAPOFF].
template<int K, int TAPOFF, int NP>
__device__ __forceinline__ void conv_acc(const float* __restrict__ wrow,
                                         const v2f* wnd, v2f* A) {
    #pragma unroll
    for (int v = 0; v < K; v++) {
        const float w = wrow[v];
        const int u = v + TAPOFF;
        if ((u & 1) == 0) {
            v2f wv; wv.x = w; wv.y = w;
            #pragma unroll
            for (int k = 0; k < NP; k++) A[k] += wv * wnd[(u >> 1) + k];
        } else {
            #pragma unroll
            for (int k = 0; k < NP; k++) {
                A[k].x += w * wnd[(u >> 1) + k].y;
                A[k].y += w * wnd[(u >> 1) + k + 1].x;
            }
        }
    }
}

// Packed strip conv, K=2H+1, H in {3,5}: halo lane+-1, hoisted then selected.
// Window f[0] = col j0-HE, HE = H+1 (even); TAPOFF = 1.
template<int H>
__device__ __forceinline__ void sconv_pk(const float* __restrict__ wt, float bb,
                                         const v2f* a, bool pm, bool np, v2f* acc) {
    constexpr int HE = H + 1;
    float pe[HE], ne[HE];
    pe[0] = 0.f;                       // pad slot (TAPOFF=1)
    #pragma unroll
    for (int i = 1; i < HE; i++) {     // cols j0-H .. j0-1 = prev elems 8-H..7
        float tmp = dppsr1(elem(a, 8 - HE + i));
        pe[i] = pm ? tmp : 0.f;
    }
    #pragma unroll
    for (int i = 0; i < H; i++) {      // cols j0+8 .. j0+8+H-1 = next elems 0..H-1
        float tmp = dppsl1(elem(a, i));
        ne[i] = np ? tmp : 0.f;
    }
    ne[H] = 0.f;
    v2f wnd[HE + 4];
    #pragma unroll
    for (int m = 0; m < HE / 2; m++) { wnd[m].x = pe[2 * m]; wnd[m].y = pe[2 * m + 1]; }
    #pragma unroll
    for (int k = 0; k < 4; k++) wnd[HE / 2 + k] = a[k];
    #pragma unroll
    for (int m = 0; m < HE / 2; m++) {
        wnd[HE / 2 + 4 + m].x = ne[2 * m]; wnd[HE / 2 + 4 + m].y = ne[2 * m + 1];
    }
    #pragma unroll
    for (int k = 0; k < 4; k++) { acc[k].x = bb; acc[k].y = bb; }
    conv_acc<2 * H + 1, 1, 4>(wt, wnd, acc);
}

// Packed 21-tap strip conv (H=10): halo lane+-1 (8 elems) + lane+-2 (2 elems).
// Window f[0] = col j0-10; TAPOFF = 0.
__device__ __forceinline__ void sconv21_pk(const float* __restrict__ wt, float bb,
                                           const v2f* a, bool pm, bool pm2,
                                           bool np, bool np2, v2f* acc) {
    float pe[10], ne[10];
    { float t0 = dppsr2(elem(a, 6)); pe[0] = pm2 ? t0 : 0.f; }
    { float t1 = dppsr2(elem(a, 7)); pe[1] = pm2 ? t1 : 0.f; }
    #pragma unroll
    for (int i = 0; i < 8; i++) {      // cols j0-8+i = prev elems 0..7
        float tmp = dppsr1(elem(a, i));
        pe[2 + i] = pm ? tmp : 0.f;
    }
    #pragma unroll
    for (int i = 0; i < 8; i++) {      // cols j0+8+i = next elems 0..7
        float tmp = dppsl1(elem(a, i));
        ne[i] = np ? tmp : 0.f;
    }
    { float t0 = dppsl2(elem(a, 0)); ne[8] = np2 ? t0 : 0.f; }
    { float t1 = dppsl2(elem(a, 1)); ne[9] = np2 ? t1 : 0.f; }
    v2f wnd[14];
    #pragma unroll
    for (int m = 0; m < 5; m++) { wnd[m].x = pe[2 * m]; wnd[m].y = pe[2 * m + 1]; }
    #pragma unroll
    for (int k = 0; k < 4; k++) wnd[5 + k] = a[k];
    #pragma unroll
    for (int m = 0; m < 5; m++) { wnd[9 + m].x = ne[2 * m]; wnd[9 + m].y = ne[2 * m + 1]; }
    #pragma unroll
    for (int k = 0; k < 4; k++) { acc[k].x = bb; acc[k].y = bb; }
    conv_acc<21, 0, 4>(wt, wnd, acc);
}

__global__ __launch_bounds__(512, 4)
void msca_fused(const float* __restrict__ x,
                const float* __restrict__ w0,   const float* __restrict__ b0,
                const float* __restrict__ w0_1, const float* __restrict__ b0_1,
                const float* __restrict__ w0_2, const float* __restrict__ b0_2,
                const float* __restrict__ w1_1, const float* __restrict__ b1_1,
                const float* __restrict__ w1_2, const float* __restrict__ b1_2,
                const float* __restrict__ w2_1, const float* __restrict__ b2_1,
                const float* __restrict__ w2_2, const float* __restrict__ b2_2,
                float* __restrict__ out)
{
    __shared__ __align__(16) float lds[LDS_WORDS];
    float* RT = lds;                // ATT_T
    float* R0 = lds + RW;           // Y0
    float* R1 = lds + 2 * RW;       // Y1
    float* R2 = lds + 3 * RW;       // Y2

    const int t     = threadIdx.x;     // 0..511
    const int maj   = t >> 3;          // X: image row ; T: image col
    const int lane8 = t & 7;
    const int j0    = lane8 << 3;

    const bool pm  = lane8 >= 1, np  = lane8 <= 6;
    const bool pm2 = lane8 >= 2, np2 = lane8 <= 5;

    const int scat = maj ^ (lane8 << 3);                           // scatter minor
    const int rdb  = maj * 68 + ((lane8 ^ ((maj >> 3) & 7)) << 3); // strip read base

    const int plane = blockIdx.x;
    const int ch    = plane & 255;

    const float* xg = x + (size_t)plane * 4096;
    float* o0 = out + (size_t)plane * 4096;
    float* o1 = o0 + 8388608;
    float* o2 = o1 + 8388608;

    // ---- P1: attn = conv5x5(x)+b0, x DIRECT from global (packed); ATT_T ----
    v2f attn[4];
    {
        const float bb = b0[ch];
        #pragma unroll
        for (int k = 0; k < 4; k++) { attn[k].x = bb; attn[k].y = bb; }
        const float* w0p = w0 + ch * 25;
        #pragma unroll
        for (int dr = 0; dr < 5; dr++) {
            const int ri = maj + dr - 2;
            const int rc = ri < 0 ? 0 : (ri > 63 ? 63 : ri);
            const bool valid = (unsigned)ri <= 63u;
            float a[8];
            ld8(&xg[rc * 64 + j0], a);
            #pragma unroll
            for (int i = 0; i < 8; i++) a[i] = valid ? a[i] : 0.f;  // row-edge zero
            float l0 = dppsr1(a[6]), l1 = dppsr1(a[7]);
            float r0 = dppsl1(a[0]), r1 = dppsl1(a[1]);
            v2f wnd[6];                       // cols j0-2 .. j0+9, f[0]=j0-2
            wnd[0].x = pm ? l0 : 0.f;  wnd[0].y = pm ? l1 : 0.f;
            wnd[1].x = a[0]; wnd[1].y = a[1];
            wnd[2].x = a[2]; wnd[2].y = a[3];
            wnd[3].x = a[4]; wnd[3].y = a[5];
            wnd[4].x = a[6]; wnd[4].y = a[7];
            wnd[5].x = np ? r0 : 0.f;  wnd[5].y = np ? r1 : 0.f;
            conv_acc<5, 0, 4>(w0p + dr * 5, wnd, attn);
        }
        #pragma unroll
        for (int e = 0; e < 8; e++) RT[(j0 + e) * 68 + scat] = elem(attn, e);
    }
    __syncthreads();   // B1 (ATT_T ready)

    // ---- P2: T-strip read; a0y -> a1y -> a2y packed chain; scatter Y0/Y1/Y2 ----
    {
        v2f stv[4];
        ld4p(&RT[rdb],     &stv[0]);
        ld4p(&RT[rdb + 4], &stv[2]);
        v2f a0y[4];
        sconv_pk<3>(w0_2 + ch * 7, b0_2[ch], stv, pm, np, a0y);
        #pragma unroll
        for (int d = 0; d < 8; d++) R0[(j0 + d) * 68 + scat] = elem(a0y, d);   // Y0
        v2f a1y[4];
        sconv_pk<5>(w1_2 + ch * 11, b1_2[ch], a0y, pm, np, a1y);
        #pragma unroll
        for (int d = 0; d < 8; d++) R1[(j0 + d) * 68 + scat] = elem(a1y, d);   // Y1
        v2f a2y[4];
        sconv21_pk(w2_2 + ch * 21, b2_2[ch], a1y, pm, pm2, np, np2, a2y);
        #pragma unroll
        for (int d = 0; d < 8; d++) R2[(j0 + d) * 68 + scat] = elem(a2y, d);   // Y2
    }
    __syncthreads();   // B2 (Y0/Y1/Y2 ready)

    // ---- P3: staggered Y reads; packed x-chain; products; stores ----
    {
        v2f y0r[4];
        ld4p(&R0[rdb],     &y0r[0]);       // issue; latency under a0x conv
        ld4p(&R0[rdb + 4], &y0r[2]);
        v2f a0x[4];
        sconv_pk<3>(w0_1 + ch * 7, b0_1[ch], attn, pm, np, a0x);
        {
            v2f q0 = a0x[0] * y0r[0], q1 = a0x[1] * y0r[1];
            v2f q2 = a0x[2] * y0r[2], q3 = a0x[3] * y0r[3];
            st4p(&o0[maj * 64 + j0],     q0, q1);
            st4p(&o0[maj * 64 + j0 + 4], q2, q3);
        }
        v2f y1r[4];
        ld4p(&R1[rdb],     &y1r[0]);       // issue; latency under a1x conv
        ld4p(&R1[rdb + 4], &y1r[2]);
        v2f a1x[4];
        sconv_pk<5>(w1_1 + ch * 11, b1_1[ch], a0x, pm, np, a1x);
        {
            v2f q0 = a1x[0] * y1r[0], q1 = a1x[1] * y1r[1];
            v2f q2 = a1x[2] * y1r[2], q3 = a1x[3] * y1r[3];
            st4p(&o1[maj * 64 + j0],     q0, q1);
            st4p(&o1[maj * 64 + j0 + 4], q2, q3);
        }
        v2f y2r[4];
        ld4p(&R2[rdb],     &y2r[0]);       // issue; latency under a2x conv
        ld4p(&R2[rdb + 4], &y2r[2]);
        v2f a2x[4];
        sconv21_pk(w2_1 + ch * 21, b2_1[ch], a1x, pm, pm2, np, np2, a2x);
        {
            v2f q0 = a2x[0] * y2r[0], q1 = a2x[1] * y2r[1];
            v2f q2 = a2x[2] * y2r[2], q3 = a2x[3] * y2r[3];
            st4p(&o2[maj * 64 + j0],     q0, q1);
            st4p(&o2[maj * 64 + j0 + 4], q2, q3);
        }
    }
}

extern "C" void kernel_launch(void* const* d_in, const int* in_sizes, int n_in,
                              void* d_out, int out_size, void* d_ws, size_t ws_size,
                              hipStream_t stream) {
    msca_fused<<<2048, 512, 0, stream>>>(
        (const float*)d_in[0],
        (const float*)d_in[1],  (const float*)d_in[2],
        (const float*)d_in[3],  (const float*)d_in[4],
        (const float*)d_in[5],  (const float*)d_in[6],
        (const float*)d_in[7],  (const float*)d_in[8],
        (const float*)d_in[9],  (const float*)d_in[10],
        (const float*)d_in[11], (const float*)d_in[12],
        (const float*)d_in[13], (const float*)d_in[14],
        (float*)d_out);
}